// Round 5
// baseline (16035.823 us; speedup 1.0000x reference)
//
#include <hip/hip_runtime.h>
#include <math.h>

typedef unsigned short u16;
typedef unsigned int   u32;
typedef __attribute__((ext_vector_type(8))) short short8;
typedef __attribute__((ext_vector_type(4))) float f32x4;

#define HID  200
#define G4   800
#define SEQT 128
#define NOUT 64
#define NTH  512
#define WKP  224

// ---------------- shared helpers ----------------
__device__ __forceinline__ float fsig(float v) {
    return __builtin_amdgcn_rcpf(1.0f + __expf(-v));
}
__device__ __forceinline__ float ftanh(float v) {
    return 1.0f - 2.0f * __builtin_amdgcn_rcpf(__expf(2.0f * v) + 1.0f);
}
__device__ __forceinline__ u16 bf16_rne(float v) {
    u32 u = __float_as_uint(v);
    u = u + 0x7FFFu + ((u >> 16) & 1u);
    return (u16)(u >> 16);
}

// ============================================================================
// FAST PATH: 8 groups x 32 CUs, weights resident in LDS, h streamed via L2
// ============================================================================
#define HST   200               // h global row stride (u16)
#define WSTR  232               // W LDS row stride (u16)
#define GSTR  34                // gates LDS row stride (f32)
#define PLN2  ((size_t)4096*HST)

#define WS_PRED 0               // predG: 16384 B
#define WS_BAR  16384           // barriers: 2048 B
#define WS_H    18432           // 8 h planes: 13,107,200 B
#define WS_TAIL (WS_H + 8*(int)(PLN2*2))
#define WS_FAST (WS_TAIL + 256)

#define L_A2   (6*32*WSTR*2)    // 89088: weights [6 planes][32 rows][232]
#define L_G2   (L_A2 + 4*14336) // +57344 staging = 146432
#define L_TOT2 (L_G2 + 64*GSTR*4) // +8704 gates = 155136

__global__ void init_fast(char* __restrict__ ws) {
    size_t n = WS_FAST / 4;
    u32* p = (u32*)ws;
    size_t stride = (size_t)gridDim.x * blockDim.x;
    for (size_t i = (size_t)blockIdx.x * blockDim.x + threadIdx.x; i < n; i += stride)
        p[i] = 0u;
}

// group barrier (32 WGs) via generation counter, agent scope
__device__ __forceinline__ void gbar(u32* barr, int g, unsigned& mygen) {
    __syncthreads();
    if (threadIdx.x == 0) {
        u32* cnt = barr + g * 64;
        u32* gen = barr + g * 64 + 32;
        unsigned target = mygen + 1;
        __threadfence();
        unsigned old = __hip_atomic_fetch_add(cnt, 1u, __ATOMIC_ACQ_REL, __HIP_MEMORY_SCOPE_AGENT);
        if (old == 31u) {
            __hip_atomic_store(cnt, 0u, __ATOMIC_RELAXED, __HIP_MEMORY_SCOPE_AGENT);
            __hip_atomic_fetch_add(gen, 1u, __ATOMIC_RELEASE, __HIP_MEMORY_SCOPE_AGENT);
        } else {
            while (__hip_atomic_load(gen, __ATOMIC_ACQUIRE, __HIP_MEMORY_SCOPE_AGENT) < target)
                __builtin_amdgcn_s_sleep(4);
        }
        __threadfence();
    }
    __syncthreads();
    mygen += 1;
}

// load this CU's N-slice of 3 fp32 matrices, split into bf16 hi/lo LDS planes
__device__ __forceinline__ void load_weights_f32(u16* Wl,
        const float* __restrict__ M0, const float* __restrict__ M1,
        const float* __restrict__ M2,
        int NRr, int cnt, int csh, int m0, int tid) {
    int tot = 3 * NRr * WKP;
    for (int idx = tid; idx < tot; idx += NTH) {
        int k   = idx % WKP;
        int rem = idx / WKP;
        int rr  = rem % NRr;
        int mi  = rem / NRr;                 // 0..2
        const float* M = (mi == 0) ? M0 : ((mi == 1) ? M1 : M2);
        int q = rr >> csh, i = rr & (cnt - 1);
        int n = 200 * q + m0 + i;
        float v = (k < HID) ? M[n * HID + k] : 0.0f;
        u16 hi = bf16_rne(v);
        float r2 = v - __uint_as_float(((u32)hi) << 16);
        u16 lo = bf16_rne(r2);
        Wl[(2 * mi)     * (32 * WSTR) + rr * WSTR + k] = hi;
        Wl[(2 * mi + 1) * (32 * WSTR) + rr * WSTR + k] = lo;
    }
}

// async stage one 64-row chunk of an h plane pair into LDS
__device__ __forceinline__ void stageA2(char* Ab, const u16* __restrict__ Ahi,
                                        const u16* __restrict__ Alo, int brow0, int w, int lane) {
    const u16* src = (w & 1) ? Alo : Ahi;
    char* lb = Ab + (w >> 1) * 14336 + (w & 1) * 7168;
    const u16* g0 = src + (size_t)(brow0 + ((w >> 1) << 4) + (lane & 15)) * HST + ((lane >> 4) << 3);
#pragma unroll
    for (int c = 0; c < 7; ++c) {
        __builtin_amdgcn_global_load_lds(
            (const __attribute__((address_space(1))) u32*)(g0 + c * 32),
            (__attribute__((address_space(3))) u32*)(lb + c * 1024),
            16, 0, 0);
    }
}

__device__ __forceinline__ void loadB2(const u16* Wl, int mp, int ntw, int lane, short8* B) {
    const u16* b0 = Wl + mp * (32 * WSTR) + (ntw * 16 + (lane & 15)) * WSTR + ((lane >> 4) << 3);
#pragma unroll
    for (int c = 0; c < 7; ++c) B[c] = *(const short8*)(b0 + c * 32);
}

__device__ __forceinline__ void mmpass2(const char* Ab, const short8* Bh, const short8* Bl,
                                        f32x4& aa, f32x4& ab, int w, int lane) {
    const char* a0 = Ab + (w >> 1) * 14336;
#pragma unroll
    for (int c = 0; c < 7; ++c) {
        short8 ahi = *(const short8*)(a0 + c * 1024 + lane * 16);
        short8 alo = *(const short8*)(a0 + 7168 + c * 1024 + lane * 16);
        if (c & 1) {
            ab = __builtin_amdgcn_mfma_f32_16x16x32_bf16(ahi, Bh[c], ab, 0, 0, 0);
            ab = __builtin_amdgcn_mfma_f32_16x16x32_bf16(ahi, Bl[c], ab, 0, 0, 0);
            ab = __builtin_amdgcn_mfma_f32_16x16x32_bf16(alo, Bh[c], ab, 0, 0, 0);
        } else {
            aa = __builtin_amdgcn_mfma_f32_16x16x32_bf16(ahi, Bh[c], aa, 0, 0, 0);
            aa = __builtin_amdgcn_mfma_f32_16x16x32_bf16(ahi, Bl[c], aa, 0, 0, 0);
            aa = __builtin_amdgcn_mfma_f32_16x16x32_bf16(alo, Bh[c], aa, 0, 0, 0);
        }
    }
}

__device__ __forceinline__ void gwrite2(float* gb, f32x4 aa, f32x4 ab, int w, int lane) {
    int row0 = ((w >> 1) << 4) + ((lane >> 4) << 2);
    int col  = (w & 1) * 16 + (lane & 15);
#pragma unroll
    for (int j = 0; j < 4; ++j) gb[(row0 + j) * GSTR + col] = aa[j] + ab[j];
}

__device__ __forceinline__ void ew2(const float* gb, float& creg,
                                    u16* __restrict__ Ohi, u16* __restrict__ Olo,
                                    int babs0, int tid, int heavy, int cnt, int csh, int m0) {
    if (heavy || tid < 256) {
        int b_loc = tid >> csh, i = tid & (cnt - 1);
        const float* gg = gb + b_loc * GSTR;
        float vi = gg[i], vf = gg[cnt + i], vg = gg[2 * cnt + i], vo = gg[3 * cnt + i];
        float cn = fsig(vf) * creg + fsig(vi) * ftanh(vg);
        creg = cn;
        float h = fsig(vo) * ftanh(cn);
        u16 hv = bf16_rne(h);
        float r2 = h - __uint_as_float(((u32)hv) << 16);
        u16 lv = bf16_rne(r2);
        size_t o = (size_t)(babs0 + b_loc) * HST + m0 + i;
        Ohi[o] = hv;
        Olo[o] = lv;
    }
}

// layer-1 cell (scalar input read from psrc with stride/offset)
__device__ __forceinline__ void cell_l1f(
    u16* Wl, char* Ab, float* gb,
    const u16* Ahi, const u16* Alo, u16* Ohi, u16* Olo,
    const float* __restrict__ psrc, int pstr, int poff,
    const float* __restrict__ wihv, const float* __restrict__ biasv, float* c1,
    int tid, int lane, int w, int ntw, int NT, int heavy, int cnt, int csh, int m0, int b0g)
{
    short8 Bh[7], Bl[7];
    float bj = 0.f, wj = 0.f;
    if (ntw < NT) {
        loadB2(Wl, 0, ntw, lane, Bh);
        loadB2(Wl, 1, ntw, lane, Bl);
        int nl = ntw * 16 + (lane & 15);
        int q = nl >> csh, i = nl & (cnt - 1);
        int n = 200 * q + m0 + i;
        bj = biasv[n];
        wj = wihv[n];
    }
#pragma unroll
    for (int ch = 0; ch < 8; ++ch) {
        stageA2(Ab, Ahi, Alo, b0g + ch * 64, w, lane);
        if (ch > 0) ew2(gb, c1[ch - 1], Ohi, Olo, b0g + (ch - 1) * 64, tid, heavy, cnt, csh, m0);
        asm volatile("s_waitcnt vmcnt(0)" ::: "memory");
        __syncthreads();
        if (ntw < NT) {
            int br0 = b0g + ch * 64 + ((w >> 1) << 4) + ((lane >> 4) << 2);
            f32x4 aa, ab = (f32x4){0.f, 0.f, 0.f, 0.f};
#pragma unroll
            for (int j = 0; j < 4; ++j) aa[j] = fmaf(psrc[(size_t)(br0 + j) * pstr + poff], wj, bj);
            mmpass2(Ab, Bh, Bl, aa, ab, w, lane);
            gwrite2(gb, aa, ab, w, lane);
        }
        __syncthreads();
    }
    ew2(gb, c1[7], Ohi, Olo, b0g + 7 * 64, tid, heavy, cnt, csh, m0);
}

// layer-2 cell (two matmuls: h1-new and h2-old)
__device__ __forceinline__ void cell_l2f(
    u16* Wl, char* Ab, float* gb,
    const u16* A1hi, const u16* A1lo, const u16* A2hi, const u16* A2lo,
    u16* Ohi, u16* Olo,
    const float* __restrict__ biasv, float* c2,
    int tid, int lane, int w, int ntw, int NT, int heavy, int cnt, int csh, int m0, int b0g)
{
    short8 B1h[7], B1l[7], B2h[7], B2l[7];
    float bj = 0.f;
    if (ntw < NT) {
        loadB2(Wl, 2, ntw, lane, B1h);
        loadB2(Wl, 3, ntw, lane, B1l);
        loadB2(Wl, 4, ntw, lane, B2h);
        loadB2(Wl, 5, ntw, lane, B2l);
        int nl = ntw * 16 + (lane & 15);
        int q = nl >> csh, i = nl & (cnt - 1);
        bj = biasv[200 * q + m0 + i];
    }
#pragma unroll
    for (int ch = 0; ch < 8; ++ch) {
        stageA2(Ab, A1hi, A1lo, b0g + ch * 64, w, lane);
        if (ch > 0) ew2(gb, c2[ch - 1], Ohi, Olo, b0g + (ch - 1) * 64, tid, heavy, cnt, csh, m0);
        asm volatile("s_waitcnt vmcnt(0)" ::: "memory");
        __syncthreads();
        f32x4 aa = (f32x4){bj, bj, bj, bj}, ab = (f32x4){0.f, 0.f, 0.f, 0.f};
        if (ntw < NT) mmpass2(Ab, B1h, B1l, aa, ab, w, lane);
        __syncthreads();                     // staging buffer free
        stageA2(Ab, A2hi, A2lo, b0g + ch * 64, w, lane);
        asm volatile("s_waitcnt vmcnt(0)" ::: "memory");
        __syncthreads();
        if (ntw < NT) {
            mmpass2(Ab, B2h, B2l, aa, ab, w, lane);
            gwrite2(gb, aa, ab, w, lane);
        }
        __syncthreads();
    }
    ew2(gb, c2[7], Ohi, Olo, b0g + 7 * 64, tid, heavy, cnt, csh, m0);
}

// decoder prediction: slice s handles 16 batch rows of the group
__device__ __forceinline__ void predp2(
    float* ps, const u16* __restrict__ H2hi, const u16* __restrict__ H2lo,
    const float* __restrict__ linW, const float* __restrict__ linb,
    float* __restrict__ predG, float* __restrict__ out,
    int sdec, int b0g, int s, int tid)
{
    int bi = tid >> 5, kk = tid & 31;
    float part = 0.f;
    size_t rb = (size_t)(b0g + s * 16 + bi) * HST;
#pragma unroll
    for (int j = 0; j < 7; ++j) {
        int k = kk + 32 * j;
        if (k < HID) {
            float hv = __uint_as_float(((u32)H2hi[rb + k]) << 16)
                     + __uint_as_float(((u32)H2lo[rb + k]) << 16);
            part = fmaf(hv, linW[k], part);
        }
    }
    ps[bi * 33 + kk] = part;
    __syncthreads();
    if (tid < 16) {
        float p = linb[0];
#pragma unroll
        for (int k2 = 0; k2 < 32; ++k2) p += ps[tid * 33 + k2];
        predG[b0g + s * 16 + tid] = p;
        out[(size_t)(b0g + s * 16 + tid) * NOUT + sdec] = p;
    }
    __syncthreads();
}

__global__ __launch_bounds__(NTH, 2)
void lstm_fast(const float* __restrict__ x,
               const float* __restrict__ eWih0, const float* __restrict__ eWhh0,
               const float* __restrict__ eB0,
               const float* __restrict__ eWih1, const float* __restrict__ eWhh1,
               const float* __restrict__ eB1,
               const float* __restrict__ dWih0, const float* __restrict__ dWhh0,
               const float* __restrict__ dB0,
               const float* __restrict__ dWih1, const float* __restrict__ dWhh1,
               const float* __restrict__ dB1,
               const float* __restrict__ linW, const float* __restrict__ linb,
               u16* hb, float* predG, u32* barr, float* __restrict__ out)
{
    extern __shared__ char sm[];
    u16*  Wl = (u16*)sm;
    char* Ab = sm + L_A2;
    float* gb = (float*)(sm + L_G2);

    const int tid = threadIdx.x, lane = tid & 63, w = tid >> 6;
    const int g = blockIdx.x & 7, s = blockIdx.x >> 3;
    const int heavy = (s < 18) ? 1 : 0;
    const int cnt = heavy ? 8 : 4;
    const int csh = heavy ? 3 : 2;
    const int m0  = heavy ? 8 * s : 144 + 4 * (s - 18);
    const int NT  = cnt >> 2;
    const int ntw = w & 1;
    const int b0g = g * 512;
    unsigned mygen = 0;

    load_weights_f32(Wl, eWhh0, eWih1, eWhh1, 4 * cnt, cnt, csh, m0, tid);
    __syncthreads();

    float c1[8], c2[8];
#pragma unroll
    for (int i = 0; i < 8; ++i) { c1[i] = 0.f; c2[i] = 0.f; }
    int p1 = 0, p2 = 0;

    // ---------------- encoder: 128 steps ----------------
    for (int t = 0; t < SEQT; ++t) {
        cell_l1f(Wl, Ab, gb,
                 hb + (size_t)(2 * p1) * PLN2, hb + (size_t)(2 * p1 + 1) * PLN2,
                 hb + (size_t)(2 * (p1 ^ 1)) * PLN2, hb + (size_t)(2 * (p1 ^ 1) + 1) * PLN2,
                 x, SEQT, t, eWih0, eB0, c1,
                 tid, lane, w, ntw, NT, heavy, cnt, csh, m0, b0g);
        p1 ^= 1;
        gbar(barr, g, mygen);
        cell_l2f(Wl, Ab, gb,
                 hb + (size_t)(2 * p1) * PLN2, hb + (size_t)(2 * p1 + 1) * PLN2,
                 hb + (size_t)(4 + 2 * p2) * PLN2, hb + (size_t)(4 + 2 * p2 + 1) * PLN2,
                 hb + (size_t)(4 + 2 * (p2 ^ 1)) * PLN2, hb + (size_t)(4 + 2 * (p2 ^ 1) + 1) * PLN2,
                 eB1, c2, tid, lane, w, ntw, NT, heavy, cnt, csh, m0, b0g);
        p2 ^= 1;
    }

    // swap to decoder weights (CU-local)
    __syncthreads();
    load_weights_f32(Wl, dWhh0, dWih1, dWhh1, 4 * cnt, cnt, csh, m0, tid);
    __syncthreads();

    // ---------------- decoder: 64 steps ----------------
    for (int sd = 0; sd < NOUT; ++sd) {
        const float* psrc = (sd == 0) ? x : predG;
        int pstr = (sd == 0) ? SEQT : 1;
        int poff = (sd == 0) ? (SEQT - 1) : 0;
        cell_l1f(Wl, Ab, gb,
                 hb + (size_t)(2 * p1) * PLN2, hb + (size_t)(2 * p1 + 1) * PLN2,
                 hb + (size_t)(2 * (p1 ^ 1)) * PLN2, hb + (size_t)(2 * (p1 ^ 1) + 1) * PLN2,
                 psrc, pstr, poff, dWih0, dB0, c1,
                 tid, lane, w, ntw, NT, heavy, cnt, csh, m0, b0g);
        p1 ^= 1;
        gbar(barr, g, mygen);
        cell_l2f(Wl, Ab, gb,
                 hb + (size_t)(2 * p1) * PLN2, hb + (size_t)(2 * p1 + 1) * PLN2,
                 hb + (size_t)(4 + 2 * p2) * PLN2, hb + (size_t)(4 + 2 * p2 + 1) * PLN2,
                 hb + (size_t)(4 + 2 * (p2 ^ 1)) * PLN2, hb + (size_t)(4 + 2 * (p2 ^ 1) + 1) * PLN2,
                 dB1, c2, tid, lane, w, ntw, NT, heavy, cnt, csh, m0, b0g);
        p2 ^= 1;
        gbar(barr, g, mygen);
        predp2(gb, hb + (size_t)(4 + 2 * p2) * PLN2, hb + (size_t)(4 + 2 * p2 + 1) * PLN2,
               linW, linb, predG, out, sd, b0g, s, tid);
        gbar(barr, g, mygen);
    }
}

// ============================================================================
// FALLBACK PATH: round-3 kernel (proven pass @ 10.3 ms, needs 4.3 MB ws)
// ============================================================================
#define BB    16
#define AST   232
#define GST   802
#define MATU  (G4 * WKP)

__global__ void prep_weights(const float* __restrict__ s0, const float* __restrict__ s1,
                             const float* __restrict__ s2, const float* __restrict__ s3,
                             const float* __restrict__ s4, const float* __restrict__ s5,
                             u16* __restrict__ ws) {
    const float* src;
    int m = blockIdx.y;
    switch (m) {
        case 0: src = s0; break;
        case 1: src = s1; break;
        case 2: src = s2; break;
        case 3: src = s3; break;
        case 4: src = s4; break;
        default: src = s5; break;
    }
    int i = blockIdx.x * blockDim.x + threadIdx.x;
    int n = i / WKP;
    int k = i - n * WKP;
    float v = (k < HID) ? src[n * HID + k] : 0.0f;
    u16 hi = bf16_rne(v);
    float rem = v - __uint_as_float(((u32)hi) << 16);
    u16 lo = bf16_rne(rem);
    ws[(size_t)(2 * m) * MATU + i]     = hi;
    ws[(size_t)(2 * m + 1) * MATU + i] = lo;
}

__device__ __forceinline__ short8 ldA_r3(const u16* h, int lane, int c) {
    return *(const short8*)(h + (lane & 15) * AST + c * 32 + ((lane >> 4) << 3));
}

template<int NT>
__device__ __forceinline__ void mm_pass_r3(const u16* __restrict__ Whi,
                                           const u16* __restrict__ Wlo,
                                           const u16* hhi, const u16* hlo,
                                           int lane, int tile0, f32x4* acc) {
    short8 ahi[7], alo[7];
#pragma unroll
    for (int c = 0; c < 7; ++c) { ahi[c] = ldA_r3(hhi, lane, c); alo[c] = ldA_r3(hlo, lane, c); }
    const int ko   = (lane >> 4) << 3;
    const int nrow = lane & 15;
#pragma unroll
    for (int t = 0; t < NT; ++t) {
        const u16* wp = Whi + (size_t)((tile0 + t) * 16 + nrow) * WKP + ko;
        const u16* wq = Wlo + (size_t)((tile0 + t) * 16 + nrow) * WKP + ko;
#pragma unroll
        for (int c = 0; c < 7; ++c) {
            short8 bhi = *(const short8*)(wp + c * 32);
            short8 blo = *(const short8*)(wq + c * 32);
            acc[t] = __builtin_amdgcn_mfma_f32_16x16x32_bf16(ahi[c], bhi, acc[t], 0, 0, 0);
            acc[t] = __builtin_amdgcn_mfma_f32_16x16x32_bf16(ahi[c], blo, acc[t], 0, 0, 0);
            acc[t] = __builtin_amdgcn_mfma_f32_16x16x32_bf16(alo[c], bhi, acc[t], 0, 0, 0);
        }
    }
}

template<int NT>
__device__ __forceinline__ void cell_mm_s_r3(float* gates,
        const u16* Whi, const u16* Wlo, const u16* hhi, const u16* hlo,
        const float* __restrict__ bias, const float* __restrict__ wih,
        const float* xcol, int lane, int tile0) {
    f32x4 acc[NT];
    const int nrow = lane & 15;
    const int bg   = (lane >> 4) << 2;
#pragma unroll
    for (int t = 0; t < NT; ++t) {
        int n = (tile0 + t) * 16 + nrow;
        float bj = bias[n], wj = wih[n];
#pragma unroll
        for (int r = 0; r < 4; ++r) acc[t][r] = fmaf(xcol[bg + r], wj, bj);
    }
    mm_pass_r3<NT>(Whi, Wlo, hhi, hlo, lane, tile0, acc);
#pragma unroll
    for (int t = 0; t < NT; ++t) {
        int n = (tile0 + t) * 16 + nrow;
#pragma unroll
        for (int r = 0; r < 4; ++r) gates[(bg + r) * GST + n] = acc[t][r];
    }
}

template<int NT>
__device__ __forceinline__ void cell_mm_v_r3(float* gates,
        const u16* Wihhi, const u16* Wihlo, const u16* Whhhi, const u16* Whhlo,
        const u16* hxhi, const u16* hxlo, const u16* hhhi, const u16* hhlo,
        const float* __restrict__ bias, int lane, int tile0) {
    f32x4 acc[NT];
    const int nrow = lane & 15;
    const int bg   = (lane >> 4) << 2;
#pragma unroll
    for (int t = 0; t < NT; ++t) {
        float bj = bias[(tile0 + t) * 16 + nrow];
        acc[t] = (f32x4){bj, bj, bj, bj};
    }
    mm_pass_r3<NT>(Wihhi, Wihlo, hxhi, hxlo, lane, tile0, acc);
    mm_pass_r3<NT>(Whhhi, Whhlo, hhhi, hhlo, lane, tile0, acc);
#pragma unroll
    for (int t = 0; t < NT; ++t) {
        int n = (tile0 + t) * 16 + nrow;
#pragma unroll
        for (int r = 0; r < 4; ++r) gates[(bg + r) * GST + n] = acc[t][r];
    }
}

__device__ __forceinline__ void cell_ew_r3(const float* gates,
                                           u16* hhi, u16* hlo, float* cv, int tid) {
#pragma unroll
    for (int r = 0; r < 7; ++r) {
        int i = tid + r * NTH;
        if (i < BB * HID) {
            int b = i / HID;
            int m = i - b * HID;
            const float* g = gates + b * GST;
            float gi = g[m], gf = g[HID + m], gg = g[2 * HID + m], go = g[3 * HID + m];
            float cp = cv[r];
            float cn = fsig(gf) * cp + fsig(gi) * ftanh(gg);
            cv[r] = cn;
            float h = fsig(go) * ftanh(cn);
            u16 hb = bf16_rne(h);
            float rem = h - __uint_as_float(((u32)hb) << 16);
            u16 lb = bf16_rne(rem);
            hhi[b * AST + m] = hb;
            hlo[b * AST + m] = lb;
        }
    }
}

__global__ __launch_bounds__(NTH, 2)
void lstm_mfma(const float* __restrict__ x,
               const float* __restrict__ eWih0, const float* __restrict__ eB0,
               const float* __restrict__ eB1,
               const float* __restrict__ dWih0, const float* __restrict__ dB0,
               const float* __restrict__ dB1,
               const float* __restrict__ linW, const float* __restrict__ linb,
               const u16* __restrict__ wst,
               float* __restrict__ out) {
    extern __shared__ char smraw[];
    float* gates = (float*)smraw;
    float* xsT   = gates + BB * GST;
    float* linWs = xsT + SEQT * BB;
    float* predb = linWs + HID;
    float* part  = predb + BB;
    u16* h1hi = (u16*)(part + BB * 4);
    u16* h1lo = h1hi + BB * AST;
    u16* h2hi = h1lo + BB * AST;
    u16* h2lo = h2hi + BB * AST;

    const u16* eWhh0hi = wst;
    const u16* eWhh0lo = wst + MATU;
    const u16* eWih1hi = wst + 2 * MATU;
    const u16* eWih1lo = wst + 3 * MATU;
    const u16* eWhh1hi = wst + 4 * MATU;
    const u16* eWhh1lo = wst + 5 * MATU;
    const u16* dWhh0hi = wst + 6 * MATU;
    const u16* dWhh0lo = wst + 7 * MATU;
    const u16* dWih1hi = wst + 8 * MATU;
    const u16* dWih1lo = wst + 9 * MATU;
    const u16* dWhh1hi = wst + 10 * MATU;
    const u16* dWhh1lo = wst + 11 * MATU;

    const int tid  = threadIdx.x;
    const int lane = tid & 63;
    const int w    = tid >> 6;
    const int b0g  = blockIdx.x * BB;
    const int tile0 = (w < 2) ? 7 * w : 14 + 6 * (w - 2);

    for (int i = tid; i < BB * AST; i += NTH) {
        h1hi[i] = 0; h1lo[i] = 0; h2hi[i] = 0; h2lo[i] = 0;
    }
    for (int i = tid; i < BB * SEQT; i += NTH) {
        int b = i >> 7, t = i & (SEQT - 1);
        xsT[t * BB + b] = x[(size_t)(b0g + b) * SEQT + t];
    }
    for (int i = tid; i < HID; i += NTH) linWs[i] = linW[i];
    float c1v[7], c2v[7];
#pragma unroll
    for (int r = 0; r < 7; ++r) { c1v[r] = 0.0f; c2v[r] = 0.0f; }
    __syncthreads();

    for (int t = 0; t < SEQT; ++t) {
        const float* xcol = xsT + t * BB;
        if (w < 2) cell_mm_s_r3<7>(gates, eWhh0hi, eWhh0lo, h1hi, h1lo, eB0, eWih0, xcol, lane, tile0);
        else       cell_mm_s_r3<6>(gates, eWhh0hi, eWhh0lo, h1hi, h1lo, eB0, eWih0, xcol, lane, tile0);
        __syncthreads();
        cell_ew_r3(gates, h1hi, h1lo, c1v, tid);
        __syncthreads();
        if (w < 2) cell_mm_v_r3<7>(gates, eWih1hi, eWih1lo, eWhh1hi, eWhh1lo, h1hi, h1lo, h2hi, h2lo, eB1, lane, tile0);
        else       cell_mm_v_r3<6>(gates, eWih1hi, eWih1lo, eWhh1hi, eWhh1lo, h1hi, h1lo, h2hi, h2lo, eB1, lane, tile0);
        __syncthreads();
        cell_ew_r3(gates, h2hi, h2lo, c2v, tid);
        __syncthreads();
    }

    if (tid < BB) predb[tid] = xsT[(SEQT - 1) * BB + tid];
    __syncthreads();

    for (int s = 0; s < NOUT; ++s) {
        if (w < 2) cell_mm_s_r3<7>(gates, dWhh0hi, dWhh0lo, h1hi, h1lo, dB0, dWih0, predb, lane, tile0);
        else       cell_mm_s_r3<6>(gates, dWhh0hi, dWhh0lo, h1hi, h1lo, dB0, dWih0, predb, lane, tile0);
        __syncthreads();
        cell_ew_r3(gates, h1hi, h1lo, c1v, tid);
        __syncthreads();
        if (w < 2) cell_mm_v_r3<7>(gates, dWih1hi, dWih1lo, dWhh1hi, dWhh1lo, h1hi, h1lo, h2hi, h2lo, dB1, lane, tile0);
        else       cell_mm_v_r3<6>(gates, dWih1hi, dWih1lo, dWhh1hi, dWhh1lo, h1hi, h1lo, h2hi, h2lo, dB1, lane, tile0);
        __syncthreads();
        cell_ew_r3(gates, h2hi, h2lo, c2v, tid);
        __syncthreads();
        if (tid < 64) {
            int b = tid >> 2, q = tid & 3;
            const u16* ph = h2hi + b * AST + q * 50;
            const u16* pl = h2lo + b * AST + q * 50;
            const float* lw = linWs + q * 50;
            float p = 0.0f;
#pragma unroll 10
            for (int k = 0; k < 50; ++k) {
                float hv = __uint_as_float(((u32)ph[k]) << 16)
                         + __uint_as_float(((u32)pl[k]) << 16);
                p = fmaf(hv, lw[k], p);
            }
            part[tid] = p;
        }
        __syncthreads();
        if (tid < BB) {
            float p = part[tid * 4] + part[tid * 4 + 1] + part[tid * 4 + 2] + part[tid * 4 + 3]
                    + linb[0];
            predb[tid] = p;
            out[(size_t)(b0g + tid) * NOUT + s] = p;
        }
        __syncthreads();
    }
}

// ============================================================================
extern "C" void kernel_launch(void* const* d_in, const int* in_sizes, int n_in,
                              void* d_out, int out_size, void* d_ws, size_t ws_size,
                              hipStream_t stream) {
    const float* x     = (const float*)d_in[0];
    const float* eWih0 = (const float*)d_in[1];
    const float* eWhh0 = (const float*)d_in[2];
    const float* eB0   = (const float*)d_in[3];
    const float* eWih1 = (const float*)d_in[4];
    const float* eWhh1 = (const float*)d_in[5];
    const float* eB1   = (const float*)d_in[6];
    const float* dWih0 = (const float*)d_in[7];
    const float* dWhh0 = (const float*)d_in[8];
    const float* dB0   = (const float*)d_in[9];
    const float* dWih1 = (const float*)d_in[10];
    const float* dWhh1 = (const float*)d_in[11];
    const float* dB1   = (const float*)d_in[12];
    const float* linW  = (const float*)d_in[13];
    const float* linb  = (const float*)d_in[14];
    float* out = (float*)d_out;
    char* ws = (char*)d_ws;

    if (ws_size >= (size_t)WS_FAST) {
        float* predG = (float*)(ws + WS_PRED);
        u32*   barr  = (u32*)(ws + WS_BAR);
        u16*   hbp   = (u16*)(ws + WS_H);

        init_fast<<<dim3(1024), dim3(256), 0, stream>>>(ws);
        (void)hipFuncSetAttribute((const void*)lstm_fast,
                                  hipFuncAttributeMaxDynamicSharedMemorySize, L_TOT2);
        lstm_fast<<<dim3(256), dim3(NTH), L_TOT2, stream>>>(
            x, eWih0, eWhh0, eB0, eWih1, eWhh1, eB1,
            dWih0, dWhh0, dB0, dWih1, dWhh1, dB1,
            linW, linb, hbp, predG, barr, out);
    } else {
        // proven round-3 path (needs 4.3 MB ws)
        u16* wst = (u16*)ws;
        prep_weights<<<dim3(MATU / 256, 6), 256, 0, stream>>>(
            eWhh0, eWih1, eWhh1, dWhh0, dWih1, dWhh1, wst);
        size_t smem = (size_t)(BB * GST + SEQT * BB + HID + BB + BB * 4) * sizeof(float)
                    + (size_t)(4 * BB * AST) * sizeof(u16);
        (void)hipFuncSetAttribute((const void*)lstm_mfma,
                                  hipFuncAttributeMaxDynamicSharedMemorySize, 160 * 1024);
        lstm_mfma<<<dim3(4096 / BB), dim3(NTH), smem, stream>>>(
            x, eWih0, eB0, eB1, dWih0, dB0, dB1, linW, linb, wst, out);
    }
}